// Round 1
// baseline (885.887 us; speedup 1.0000x reference)
//
#include <hip/hip_runtime.h>

#define BLOCK 256
#define ROW_D 16384
#define VPT (ROW_D / (BLOCK * 4))  // 16 float4 per thread = 64 floats

// Monotonic bijection: float order == unsigned order of key.
__device__ __forceinline__ unsigned keyOf(float f) {
    unsigned u = __float_as_uint(f);
    return (u & 0x80000000u) ? ~u : (u | 0x80000000u);
}
__device__ __forceinline__ float valOf(unsigned m) {
    unsigned u = (m & 0x80000000u) ? (m & 0x7FFFFFFFu) : ~m;
    return __uint_as_float(u);
}

__global__ __launch_bounds__(BLOCK, 4)
void TopKActivation_68324339745162_kernel(const float* __restrict__ in,
                                          float* __restrict__ out,
                                          const int* __restrict__ kptr) {
    // hist[bin][copy]: copy = lane%32 -> LDS bank = copy, so histogram atomics
    // never bank-conflict more than 2-way regardless of digit distribution.
    __shared__ unsigned hist[256 * 32];   // 32 KiB
    __shared__ unsigned S[256];           // scan buffer
    __shared__ unsigned sDigit, sGreater, sBinCnt, sBase;

    const int t = threadIdx.x;
    const unsigned cpy = (unsigned)t & 31u;
    const size_t rowOff = (size_t)blockIdx.x * (size_t)ROW_D;
    const float4* inRow = reinterpret_cast<const float4*>(in + rowOff);
    float4* outRow = reinterpret_cast<float4*>(out + rowOff);

    // ---- Load row: keys live in registers (64 VGPRs) ----
    uint4 keys[VPT];
#pragma unroll
    for (int j = 0; j < VPT; ++j) {
        float4 v = inRow[t + BLOCK * j];
        keys[j].x = keyOf(v.x);
        keys[j].y = keyOf(v.y);
        keys[j].z = keyOf(v.z);
        keys[j].w = keyOf(v.w);
    }

    unsigned rank = (unsigned)(*kptr);   // k-th largest, rank >= 1
    unsigned prefix = 0u, pmask = 0u;

    // ---- 4x 8-bit radix select (MSB first) for the k-th largest key ----
    for (int pass = 0; pass < 4; ++pass) {
        const int shift = 24 - 8 * pass;
        for (int i = t; i < 256 * 32; i += BLOCK) hist[i] = 0u;
        __syncthreads();
#pragma unroll
        for (int j = 0; j < VPT; ++j) {
            unsigned kk;
            kk = keys[j].x;
            if ((kk & pmask) == prefix) atomicAdd(&hist[(((kk >> shift) & 255u) << 5) | cpy], 1u);
            kk = keys[j].y;
            if ((kk & pmask) == prefix) atomicAdd(&hist[(((kk >> shift) & 255u) << 5) | cpy], 1u);
            kk = keys[j].z;
            if ((kk & pmask) == prefix) atomicAdd(&hist[(((kk >> shift) & 255u) << 5) | cpy], 1u);
            kk = keys[j].w;
            if ((kk & pmask) == prefix) atomicAdd(&hist[(((kk >> shift) & 255u) << 5) | cpy], 1u);
        }
        __syncthreads();
        // Reduce 32 copies; rotated start so all lanes hit distinct banks.
        unsigned c = 0u;
#pragma unroll
        for (int i = 0; i < 32; ++i) c += hist[((unsigned)t << 5) | (unsigned)((t + i) & 31)];
        S[t] = c;
        __syncthreads();
        // Inclusive suffix sum: S[b] = count of candidates with digit >= b.
        for (int step = 1; step < 256; step <<= 1) {
            unsigned v = (t + step < 256) ? S[t + step] : 0u;
            __syncthreads();
            c += v;
            S[t] = c;
            __syncthreads();
        }
        unsigned Snext = (t < 255) ? S[t + 1] : 0u;
        if (c >= rank && Snext < rank) {   // unique by monotonicity of suffix sums
            sDigit   = (unsigned)t;
            sGreater = Snext;              // candidates strictly above this digit
            sBinCnt  = c - Snext;          // candidates in this digit bin
        }
        __syncthreads();
        rank -= sGreater;
        prefix |= sDigit << shift;
        pmask  |= 255u << shift;
    }

    const unsigned T = prefix;        // exact key of the k-th largest element
    const unsigned need = rank;       // how many ties (== T) to accept
    const bool fastTies = (sBinCnt == need);  // block-uniform

    if (fastTies) {
        // Common case: accept every element == T (usually exactly one).
#pragma unroll
        for (int j = 0; j < VPT; ++j) {
            float4 o;
            o.x = (keys[j].x >= T) ? valOf(keys[j].x) : 0.0f;
            o.y = (keys[j].y >= T) ? valOf(keys[j].y) : 0.0f;
            o.z = (keys[j].z >= T) ? valOf(keys[j].z) : 0.0f;
            o.w = (keys[j].w >= T) ? valOf(keys[j].w) : 0.0f;
            outRow[t + BLOCK * j] = o;
        }
    } else {
        // Cold path: duplicated threshold value — accept the `need` ties with
        // smallest global index (matches top_k's stable tie-break).
        // Element at (j, t, c) has global index 1024*j + 4*t + c, so iterating
        // j-major with a per-j prefix scan over threads enumerates index order.
        if (t == 0) sBase = 0u;
        for (int j = 0; j < VPT; ++j) {
            unsigned lc = (unsigned)(keys[j].x == T) + (unsigned)(keys[j].y == T) +
                          (unsigned)(keys[j].z == T) + (unsigned)(keys[j].w == T);
            __syncthreads();
            S[t] = lc;
            __syncthreads();
            unsigned run = lc;
            for (int step = 1; step < 256; step <<= 1) {
                unsigned v = (t >= step) ? S[t - step] : 0u;
                __syncthreads();
                run += v;
                S[t] = run;
                __syncthreads();
            }
            unsigned r = run - lc + sBase;  // ties before my first element
            float4 o;
            {
                unsigned kk = keys[j].x;
                if (kk > T) o.x = valOf(kk);
                else if (kk == T) { o.x = (r < need) ? valOf(kk) : 0.0f; ++r; }
                else o.x = 0.0f;
            }
            {
                unsigned kk = keys[j].y;
                if (kk > T) o.y = valOf(kk);
                else if (kk == T) { o.y = (r < need) ? valOf(kk) : 0.0f; ++r; }
                else o.y = 0.0f;
            }
            {
                unsigned kk = keys[j].z;
                if (kk > T) o.z = valOf(kk);
                else if (kk == T) { o.z = (r < need) ? valOf(kk) : 0.0f; ++r; }
                else o.z = 0.0f;
            }
            {
                unsigned kk = keys[j].w;
                if (kk > T) o.w = valOf(kk);
                else if (kk == T) { o.w = (r < need) ? valOf(kk) : 0.0f; ++r; }
                else o.w = 0.0f;
            }
            outRow[t + BLOCK * j] = o;
            __syncthreads();
            if (t == BLOCK - 1) sBase += run;   // run == total ties this j
        }
    }
}

extern "C" void kernel_launch(void* const* d_in, const int* in_sizes, int n_in,
                              void* d_out, int out_size, void* d_ws, size_t ws_size,
                              hipStream_t stream) {
    const float* in = (const float*)d_in[0];
    const int* kptr = (const int*)d_in[1];
    float* out = (float*)d_out;
    const int N = in_sizes[0] / ROW_D;   // 8192 rows
    TopKActivation_68324339745162_kernel<<<dim3(N), dim3(BLOCK), 0, stream>>>(in, out, kptr);
}